// Round 5
// baseline (82.938 us; speedup 1.0000x reference)
//
#include <hip/hip_runtime.h>
#include <hip/hip_bf16.h>

#define N_SOURCE   100000
#define N_TARGET   4096
#define SOURCE_DIM 512
#define EMBED_DIM  32
#define TARGET_DIM 16
#define NTILES     (N_SOURCE / 16)   // 6250 row-tiles of 16 (exact)
#define TILES_PER_WAVE 2

typedef __attribute__((ext_vector_type(8))) short short8;   // 8 bf16 (4 VGPR)
typedef __attribute__((ext_vector_type(4))) float f32x4;    // MFMA acc / vec loads

static __device__ __forceinline__ ushort f2bf(float f) {
    __hip_bfloat16 h = __float2bfloat16(f);   // RNE
    return *(ushort*)&h;
}

// ---------------------------------------------------------------------------
// Kernel 0: Mt = bf16( (embed @ weight)^T )   [16][512]  (folds both GEMMs)
// ---------------------------------------------------------------------------
__global__ __launch_bounds__(256)
void k_embed_weight(const float* __restrict__ embed,   // [512][32]
                    const float* __restrict__ weight,  // [32][16]
                    ushort* __restrict__ Mt) {         // [16][512] bf16
    __shared__ float wlds[EMBED_DIM * TARGET_DIM];
    int tid = threadIdx.x;
    for (int i = tid; i < EMBED_DIM * TARGET_DIM; i += 256)
        wlds[i] = weight[i];
    __syncthreads();

    int idx = blockIdx.x * 256 + tid;                  // 0..8191
    if (idx < SOURCE_DIM * TARGET_DIM) {
        int k = idx >> 4;        // K index
        int o = idx & 15;        // output col
        float s = 0.f;
        #pragma unroll
        for (int j = 0; j < EMBED_DIM; ++j)
            s += embed[k * EMBED_DIM + j] * wlds[j * TARGET_DIM + o];
        Mt[o * SOURCE_DIM + k] = f2bf(s);              // transposed store
    }
}

// ---------------------------------------------------------------------------
// Kernel 1: y[r][:] = bf16( (source_feat[r][:] @ M) / x_norm[r] )  via MFMA.
// One wave = 16-row tile; B (Mt) preloaded into 64 VGPRs; A streamed
// nontemporal from global (read-once, don't thrash L2), cvt f32->bf16 in-reg.
// Tile loop unrolls cleanly (clamp instead of break -> cross-tile pipelining;
// duplicate recompute of the last tile writes identical values, benign).
// A-frag: lane holds A[lane&15][kk*32 + (lane>>4)*8 + i]
// B-frag: lane holds B[kk*32 + (lane>>4)*8 + i][lane&15]  (Mt rows contiguous)
// C/D   : col = lane&15, row = (lane>>4)*4 + reg          (m89-verified)
// ---------------------------------------------------------------------------
__global__ __launch_bounds__(256, 2)
void k_gemm_y(const float*  __restrict__ A,      // source_feat [N_SOURCE][512]
              const float*  __restrict__ xnorm,  // [N_SOURCE]
              const ushort* __restrict__ Mt,     // [16][512] bf16
              ushort*       __restrict__ y) {    // [N_SOURCE][16] bf16
    int tid  = threadIdx.x;
    int wave = tid >> 6;
    int lane = tid & 63;
    int n    = lane & 15;     // A row within tile / B col / C col
    int g    = lane >> 4;     // k-group 0..3

    // preload B fragments (whole Mt: 16 chunks x 16B/lane, L2-hot)
    short8 bfrag[16];
    #pragma unroll
    for (int kk = 0; kk < 16; ++kk)
        bfrag[kk] = *(const short8*)(Mt + n * SOURCE_DIM + kk * 32 + g * 8);

    int tbase = blockIdx.x * (4 * TILES_PER_WAVE) + wave * TILES_PER_WAVE;

    #pragma unroll
    for (int t = 0; t < TILES_PER_WAVE; ++t) {
        int tile = tbase + t;
        tile = tile < NTILES ? tile : NTILES - 1;      // clamp, no break
        int row0 = tile * 16;
        const f32x4* Arow =
            (const f32x4*)(A + (size_t)(row0 + n) * SOURCE_DIM + g * 8);

        f32x4 acc = {0.f, 0.f, 0.f, 0.f};
        #pragma unroll
        for (int kk = 0; kk < 16; ++kk) {
            f32x4 a0 = __builtin_nontemporal_load(Arow + kk * 8);
            f32x4 a1 = __builtin_nontemporal_load(Arow + kk * 8 + 1);
            short8 af;
            af[0] = (short)f2bf(a0[0]); af[1] = (short)f2bf(a0[1]);
            af[2] = (short)f2bf(a0[2]); af[3] = (short)f2bf(a0[3]);
            af[4] = (short)f2bf(a1[0]); af[5] = (short)f2bf(a1[1]);
            af[6] = (short)f2bf(a1[2]); af[7] = (short)f2bf(a1[3]);
            acc = __builtin_amdgcn_mfma_f32_16x16x32_bf16(af, bfrag[kk], acc, 0, 0, 0);
        }

        // epilogue: lane holds C[g*4 + r][n], r = 0..3
        int m0 = g * 4;
        float4 xn = *(const float4*)(xnorm + row0 + m0);   // 16B aligned
        const float xr[4] = {xn.x, xn.y, xn.z, xn.w};
        #pragma unroll
        for (int r = 0; r < 4; ++r)
            y[(size_t)(row0 + m0 + r) * TARGET_DIM + n] = f2bf(acc[r] / xr[r]);
    }
}

// ---------------------------------------------------------------------------
// Kernel 2: out[t][:] = mean over edges of y[src[e]][:]   (y is bf16)
// ONE WAVE per target (no LDS, no barriers). 32 edge slots x 2 lanes
// (16 B bf16 each); 25 uniform iterations; butterfly over lane bits 1..5;
// lanes 0/1 store the two float4-pairs.
// ---------------------------------------------------------------------------
__global__ __launch_bounds__(256)
void k_gather_mean(const ushort* __restrict__ y,   // [N_SOURCE][16] bf16
                   const int*    __restrict__ src, // edge sources
                   const int*    __restrict__ rl,  // range_list [N_TARGET][2]
                   float* __restrict__ out) {      // [N_TARGET][16] f32
    int t    = blockIdx.x * 4 + (threadIdx.x >> 6);  // target = global wave id
    int lane = threadIdx.x & 63;
    int start = rl[2 * t];
    int end   = rl[2 * t + 1];

    int slot = lane >> 1;         // 0..31
    int sub  = lane & 1;          // which 16B half of the 32B row

    float a[8];
    #pragma unroll
    for (int i = 0; i < 8; ++i) a[i] = 0.f;

    int e = start + slot;
    int s_cur = (e < end) ? src[e] : 0;
    while (e < end) {
        int e2 = e + 32;
        int s_nxt = (e2 < end) ? src[e2] : 0;     // prefetch next index
        uint4 v = *(const uint4*)(y + (size_t)s_cur * TARGET_DIM + sub * 8);
        const uint w[4] = {v.x, v.y, v.z, v.w};
        #pragma unroll
        for (int i = 0; i < 4; ++i) {
            uint lo = w[i] << 16;
            uint hi = w[i] & 0xffff0000u;
            a[2 * i]     += *(float*)&lo;
            a[2 * i + 1] += *(float*)&hi;
        }
        e = e2; s_cur = s_nxt;
    }

    // butterfly over slot bits (lane bits 1..5); sub halves stay separate
    #pragma unroll
    for (int m = 2; m <= 32; m <<= 1) {
        #pragma unroll
        for (int i = 0; i < 8; ++i) a[i] += __shfl_xor(a[i], m);
    }

    if (lane < 2) {               // lane0 = cols 0..7, lane1 = cols 8..15
        float deg = (float)(end - start);
        deg = deg > 1.f ? deg : 1.f;
        float inv = 1.0f / deg;
        float4* o4 = (float4*)(out + t * TARGET_DIM + lane * 8);
        o4[0] = make_float4(a[0] * inv, a[1] * inv, a[2] * inv, a[3] * inv);
        o4[1] = make_float4(a[4] * inv, a[5] * inv, a[6] * inv, a[7] * inv);
    }
}

// ---------------------------------------------------------------------------
extern "C" void kernel_launch(void* const* d_in, const int* in_sizes, int n_in,
                              void* d_out, int out_size, void* d_ws, size_t ws_size,
                              hipStream_t stream) {
    const float* source_feat = (const float*)d_in[0];  // [100000][512]
    const float* embed       = (const float*)d_in[1];  // [512][32]
    const float* weight      = (const float*)d_in[2];  // [32][16]
    const int*   edge_src    = (const int*)d_in[3];    // edge_index[0][:]
    const int*   range_list  = (const int*)d_in[4];    // [4096][2]
    const float* x_norm      = (const float*)d_in[5];  // [100000]

    float*  out = (float*)d_out;
    ushort* Mt  = (ushort*)d_ws;                        // 16 KB bf16 [16][512]
    ushort* y   = (ushort*)((char*)d_ws + 16384);       // 3.2 MB bf16

    k_embed_weight<<<32, 256, 0, stream>>>(embed, weight, Mt);

    int nblk = (NTILES + 4 * TILES_PER_WAVE - 1) / (4 * TILES_PER_WAVE);  // 782
    k_gemm_y<<<nblk, 256, 0, stream>>>(source_feat, x_norm, Mt, y);

    k_gather_mean<<<N_TARGET / 4, 256, 0, stream>>>(y, edge_src, range_list, out);
}

// Round 6
// 71.668 us; speedup vs baseline: 1.1573x; 1.1573x over previous
//
#include <hip/hip_runtime.h>
#include <hip/hip_bf16.h>

#define N_SOURCE   100000
#define N_TARGET   4096
#define SOURCE_DIM 512
#define EMBED_DIM  32
#define TARGET_DIM 16
#define NTILES     (N_SOURCE / 16)   // 6250 row-tiles of 16 (exact)
#define TILES_PER_WAVE 2

typedef __attribute__((ext_vector_type(8))) short short8;   // 8 bf16 (4 VGPR)
typedef __attribute__((ext_vector_type(4))) float f32x4;    // MFMA accumulator

static __device__ __forceinline__ ushort f2bf(float f) {
    __hip_bfloat16 h = __float2bfloat16(f);   // RNE
    return *(ushort*)&h;
}

// ---------------------------------------------------------------------------
// Kernel 0: Mt = bf16( (embed @ weight)^T )   [16][512]  (folds both GEMMs)
// ---------------------------------------------------------------------------
__global__ __launch_bounds__(256)
void k_embed_weight(const float* __restrict__ embed,   // [512][32]
                    const float* __restrict__ weight,  // [32][16]
                    ushort* __restrict__ Mt) {         // [16][512] bf16
    __shared__ float wlds[EMBED_DIM * TARGET_DIM];
    int tid = threadIdx.x;
    for (int i = tid; i < EMBED_DIM * TARGET_DIM; i += 256)
        wlds[i] = weight[i];
    __syncthreads();

    int idx = blockIdx.x * 256 + tid;                  // 0..8191
    if (idx < SOURCE_DIM * TARGET_DIM) {
        int k = idx >> 4;        // K index
        int o = idx & 15;        // output col
        float s = 0.f;
        #pragma unroll
        for (int j = 0; j < EMBED_DIM; ++j)
            s += embed[k * EMBED_DIM + j] * wlds[j * TARGET_DIM + o];
        Mt[o * SOURCE_DIM + k] = f2bf(s);              // transposed store
    }
}

// ---------------------------------------------------------------------------
// Kernel 1 (identical to round-4 version, known 71.5 us config):
// y[r][:] = bf16( (source_feat[r][:] @ M) / x_norm[r] )  via MFMA.
// A-frag: lane holds A[lane&15][kk*32 + (lane>>4)*8 + i]
// B-frag: lane holds B[kk*32 + (lane>>4)*8 + i][lane&15]  (Mt rows contiguous)
// C/D   : col = lane&15, row = (lane>>4)*4 + reg          (m89-verified)
// ---------------------------------------------------------------------------
__global__ __launch_bounds__(256, 2)
void k_gemm_y(const float*  __restrict__ A,      // source_feat [N_SOURCE][512]
              const float*  __restrict__ xnorm,  // [N_SOURCE]
              const ushort* __restrict__ Mt,     // [16][512] bf16
              ushort*       __restrict__ y) {    // [N_SOURCE][16] bf16
    int tid  = threadIdx.x;
    int wave = tid >> 6;
    int lane = tid & 63;
    int n    = lane & 15;     // A row within tile / B col / C col
    int g    = lane >> 4;     // k-group 0..3

    // preload B fragments (whole Mt: 16 chunks x 16B/lane, L2-hot)
    short8 bfrag[16];
    #pragma unroll
    for (int kk = 0; kk < 16; ++kk)
        bfrag[kk] = *(const short8*)(Mt + n * SOURCE_DIM + kk * 32 + g * 8);

    int tbase = blockIdx.x * (4 * TILES_PER_WAVE) + wave * TILES_PER_WAVE;

    #pragma unroll
    for (int t = 0; t < TILES_PER_WAVE; ++t) {
        int tile = tbase + t;
        if (tile >= NTILES) break;
        int row0 = tile * 16;
        const float* Arow = A + (size_t)(row0 + n) * SOURCE_DIM + g * 8;

        f32x4 acc = {0.f, 0.f, 0.f, 0.f};
        #pragma unroll
        for (int kk = 0; kk < 16; ++kk) {
            float4 a0 = *(const float4*)(Arow + kk * 32);
            float4 a1 = *(const float4*)(Arow + kk * 32 + 4);
            short8 af;
            af[0] = (short)f2bf(a0.x); af[1] = (short)f2bf(a0.y);
            af[2] = (short)f2bf(a0.z); af[3] = (short)f2bf(a0.w);
            af[4] = (short)f2bf(a1.x); af[5] = (short)f2bf(a1.y);
            af[6] = (short)f2bf(a1.z); af[7] = (short)f2bf(a1.w);
            acc = __builtin_amdgcn_mfma_f32_16x16x32_bf16(af, bfrag[kk], acc, 0, 0, 0);
        }

        // epilogue: lane holds C[g*4 + r][n], r = 0..3
        int m0 = g * 4;
        float4 xn = *(const float4*)(xnorm + row0 + m0);   // 16B aligned
        const float xr[4] = {xn.x, xn.y, xn.z, xn.w};
        #pragma unroll
        for (int r = 0; r < 4; ++r)
            y[(size_t)(row0 + m0 + r) * TARGET_DIM + n] = f2bf(acc[r] / xr[r]);
    }
}

// ---------------------------------------------------------------------------
// Kernel 2: out[t][:] = mean over edges of y[src[e]][:]   (y is bf16)
// Block per target (4096 blocks). Each thread: one int4 index load ->
// 4 INDEPENDENT uint4 gathers in flight (ILP 4). slot=tid>>1 handles edges
// [slot*4, slot*4+4) of each 512-edge chunk; sub=tid&1 picks the 16B half.
// 800 = 512 + 72*4, so active slots always process full quads on this data.
// ---------------------------------------------------------------------------
__global__ __launch_bounds__(256)
void k_gather_mean(const ushort* __restrict__ y,   // [N_SOURCE][16] bf16
                   const int*    __restrict__ src, // edge sources
                   const int*    __restrict__ rl,  // range_list [N_TARGET][2]
                   float* __restrict__ out) {      // [N_TARGET][16] f32
    int t     = blockIdx.x;
    int tid   = threadIdx.x;
    int start = rl[2 * t];
    int end   = rl[2 * t + 1];

    int slot = tid >> 1;          // 0..127
    int sub  = tid & 1;           // which 16B half of the 32B row

    float a[8];
    #pragma unroll
    for (int i = 0; i < 8; ++i) a[i] = 0.f;

    for (int base = start + slot * 4; base < end; base += 512) {
        int rem = end - base;     // >= 1 here
        int id[4];
        if (rem >= 4) {           // aligned: start%4==0 (range starts 800*t)
            int4 q = *(const int4*)(src + base);
            id[0] = q.x; id[1] = q.y; id[2] = q.z; id[3] = q.w;
        } else {
            #pragma unroll
            for (int j = 0; j < 4; ++j) id[j] = (j < rem) ? src[base + j] : 0;
        }
        #pragma unroll
        for (int j = 0; j < 4; ++j) {
            if (j < rem) {
                uint4 v = *(const uint4*)(y + (size_t)id[j] * TARGET_DIM + sub * 8);
                const uint w[4] = {v.x, v.y, v.z, v.w};
                #pragma unroll
                for (int i = 0; i < 4; ++i) {
                    uint lo = w[i] << 16;
                    uint hi = w[i] & 0xffff0000u;
                    a[2 * i]     += *(float*)&lo;
                    a[2 * i + 1] += *(float*)&hi;
                }
            }
        }
    }

    // butterfly over slot bits within the wave (lane bits 1..5)
    #pragma unroll
    for (int m = 2; m <= 32; m <<= 1) {
        #pragma unroll
        for (int i = 0; i < 8; ++i) a[i] += __shfl_xor(a[i], m);
    }

    __shared__ float red[4][16];
    int wid  = tid >> 6;
    int lane = tid & 63;
    if (lane < 2) {               // lane0 = cols 0..7, lane1 = cols 8..15
        #pragma unroll
        for (int i = 0; i < 8; ++i) red[wid][lane * 8 + i] = a[i];
    }
    __syncthreads();

    if (tid < TARGET_DIM) {
        float s = red[0][tid] + red[1][tid] + red[2][tid] + red[3][tid];
        float deg = (float)(end - start);
        deg = deg > 1.f ? deg : 1.f;
        out[t * TARGET_DIM + tid] = s / deg;
    }
}

// ---------------------------------------------------------------------------
extern "C" void kernel_launch(void* const* d_in, const int* in_sizes, int n_in,
                              void* d_out, int out_size, void* d_ws, size_t ws_size,
                              hipStream_t stream) {
    const float* source_feat = (const float*)d_in[0];  // [100000][512]
    const float* embed       = (const float*)d_in[1];  // [512][32]
    const float* weight      = (const float*)d_in[2];  // [32][16]
    const int*   edge_src    = (const int*)d_in[3];    // edge_index[0][:]
    const int*   range_list  = (const int*)d_in[4];    // [4096][2]
    const float* x_norm      = (const float*)d_in[5];  // [100000]

    float*  out = (float*)d_out;
    ushort* Mt  = (ushort*)d_ws;                        // 16 KB bf16 [16][512]
    ushort* y   = (ushort*)((char*)d_ws + 16384);       // 3.2 MB bf16

    k_embed_weight<<<32, 256, 0, stream>>>(embed, weight, Mt);

    int nblk = (NTILES + 4 * TILES_PER_WAVE - 1) / (4 * TILES_PER_WAVE);  // 782
    k_gemm_y<<<nblk, 256, 0, stream>>>(source_feat, x_norm, Mt, y);

    k_gather_mean<<<N_TARGET, 256, 0, stream>>>(y, edge_src, range_list, out);
}